// Round 2
// baseline (338.312 us; speedup 1.0000x reference)
//
#include <hip/hip_runtime.h>

#define BB 4
#define NN 16384
#define SS 4096
#define CC 256
#define CHUNK 1024  // k points staged per LDS chunk
#define NCHUNK (SS / CHUNK)
#define RQ 4        // queries per thread (register-tiled)
#define TILE_LD 260 // padded leading dim for out-transpose tile

__device__ __forceinline__ bool lexlt(float da, int ia, float db, int ib) {
  // strict (d, idx) lexicographic order — matches jax.lax.top_k tie-break
  return (da < db) || ((da == db) && (ia < ib));
}

// ---------------- Kernel A: brute-force top-3 scan ----------------
// 512 blocks x 256 threads; 128 queries/block; LDS = 16 KB k-chunk (merge
// buffers overlaid) -> 5 blocks/CU instead of 2.
__global__ __launch_bounds__(256, 5) void scan_kernel(
    const float* __restrict__ qg, const float* __restrict__ kg,
    int4* __restrict__ idx_out, float4* __restrict__ w_out) {
#pragma clang fp contract(off)
  __shared__ __align__(16) float4 kpts[CHUNK];  // 16 KB
  float* md = (float*)kpts;                     // [4][32][4][3] floats (6 KB), overlaid
  int* mi = (int*)((char*)kpts + 6144);         // [4][32][4][3] ints (6 KB)

  const int tid = threadIdx.x;
  const int blk = blockIdx.x;
  const int b = blk >> 7;
  const int n0 = (blk & 127) << 7;
  const int qlane = tid & 31;  // 32 query-lanes
  const int g = tid >> 5;      // 8 s-groups (2 per wave)

  float qx[RQ], qy[RQ], qz[RQ], qq[RQ];
  float d0[RQ], d1[RQ], d2[RQ];
  int i0[RQ], i1[RQ], i2[RQ];
#pragma unroll
  for (int j = 0; j < RQ; ++j) {
    int n = n0 + qlane + 32 * j;
    const float* qp = qg + ((long)b * NN + n) * 3;
    qx[j] = qp[0]; qy[j] = qp[1]; qz[j] = qp[2];
    qq[j] = (qx[j] * qx[j] + qy[j] * qy[j]) + qz[j] * qz[j];  // np sum order
    d0[j] = 3.4e38f; d1[j] = 3.4e38f; d2[j] = 3.4e38f;
    i0[j] = 0; i1[j] = 0; i2[j] = 0;
  }

  const float* kb = kg + (long)b * SS * 3;

  for (int c = 0; c < NCHUNK; ++c) {
    __syncthreads();  // protect kpts from previous chunk's readers
    {
      const float4* src = (const float4*)(kb + (long)c * CHUNK * 3) + tid * 3;
      float4 f0 = src[0], f1 = src[1], f2 = src[2];
      float px[4] = {f0.x, f0.w, f1.z, f2.y};
      float py[4] = {f0.y, f1.x, f1.w, f2.z};
      float pz[4] = {f0.z, f1.y, f2.x, f2.w};
#pragma unroll
      for (int m = 0; m < 4; ++m) {
        float kk = (px[m] * px[m] + py[m] * py[m]) + pz[m] * pz[m];
        kpts[tid * 4 + m] = make_float4(px[m], py[m], pz[m], kk);
      }
    }
    __syncthreads();

    const int sbase = c * CHUNK + g * 128;
#pragma unroll 2
    for (int i = 0; i < 128; ++i) {
      float4 kp = kpts[g * 128 + i];
      const int s = sbase + i;
      float dd[RQ];
      bool c2[RQ];
      bool h = false;
#pragma unroll
      for (int j = 0; j < RQ; ++j) {
        // exact np replication: d = qq - 2*dot + kk, left-to-right, no contract.
        float dot = (qx[j] * kp.x + qy[j] * kp.y) + qz[j] * kp.z;
        dd[j] = __builtin_fmaf(dot, -2.0f, qq[j]) + kp.w;
        c2[j] = dd[j] < d2[j];
        h = h | c2[j];
      }
      // wave-uniform skip: if no lane improves any of its 4 queries, the
      // insert is a no-op for the whole wave.
      if (__any(h)) {
#pragma unroll
        for (int j = 0; j < RQ; ++j) {
          float d = dd[j];
          bool k2 = c2[j];
          bool k1 = d < d1[j];
          bool k0 = d < d0[j];
          float nd2 = fminf(fmaxf(d, d1[j]), d2[j]);  // med3 pattern
          float nd1 = fminf(fmaxf(d, d0[j]), d1[j]);
          float nd0 = fminf(d, d0[j]);
          i2[j] = k1 ? i1[j] : (k2 ? s : i2[j]);
          i1[j] = k0 ? i0[j] : (k1 ? s : i1[j]);
          i0[j] = k0 ? s : i0[j];
          d2[j] = nd2; d1[j] = nd1; d0[j] = nd0;
        }
      }
    }
  }

  // ---- intra-wave pair merge: lane L and L^32 hold the same 4 queries ----
#pragma unroll
  for (int j = 0; j < RQ; ++j) {
    float E0 = __shfl_xor(d0[j], 32), E1 = __shfl_xor(d1[j], 32), E2 = __shfl_xor(d2[j], 32);
    int F0 = __shfl_xor(i0[j], 32), F1 = __shfl_xor(i1[j], 32), F2 = __shfl_xor(i2[j], 32);
    float A0 = d0[j], A1 = d1[j], A2 = d2[j];
    int B0 = i0[j], B1 = i1[j], B2 = i2[j];
    // branchless 3-way merge of two sorted triples
    bool t = lexlt(E0, F0, A0, B0);
    float r0 = t ? E0 : A0; int s0 = t ? F0 : B0;
    float nA0 = t ? A0 : A1, nA1 = t ? A1 : A2;
    int nB0 = t ? B0 : B1, nB1 = t ? B1 : B2;
    float nE0 = t ? E1 : E0, nE1 = t ? E2 : E1;
    int nF0 = t ? F1 : F0, nF1 = t ? F2 : F1;
    bool u = lexlt(nE0, nF0, nA0, nB0);
    float r1 = u ? nE0 : nA0; int s1 = u ? nF0 : nB0;
    float mA0 = u ? nA0 : nA1; int mB0 = u ? nB0 : nB1;
    float mE0 = u ? nE1 : nE0; int mF0 = u ? nF1 : nF0;
    bool w = lexlt(mE0, mF0, mA0, mB0);
    float r2 = w ? mE0 : mA0; int s2 = w ? mF0 : mB0;
    d0[j] = r0; d1[j] = r1; d2[j] = r2;
    i0[j] = s0; i1[j] = s1; i2[j] = s2;
  }

  __syncthreads();  // all kpts reads done; md/mi overlay kpts
  if ((tid & 63) < 32) {
    const int wv = tid >> 6;
#pragma unroll
    for (int j = 0; j < RQ; ++j) {
      int base = (((wv * 32) + qlane) * RQ + j) * 3;
      md[base + 0] = d0[j]; md[base + 1] = d1[j]; md[base + 2] = d2[j];
      mi[base + 0] = i0[j]; mi[base + 1] = i1[j]; mi[base + 2] = i2[j];
    }
  }
  __syncthreads();

  if (tid < 128) {
    const int qi = tid;
    const int ql = qi & 31, jj = qi >> 5;
    float D0 = 3.4e38f, D1 = 3.4e38f, D2 = 3.4e38f;
    int I0 = -1, I1 = -1, I2 = -1;
    for (int wv = 0; wv < 4; ++wv) {
      int base = ((wv * 32 + ql) * RQ + jj) * 3;
      for (int r = 0; r < 3; ++r) {
        float d = md[base + r];
        int s = mi[base + r];
        if (lexlt(d, s, D2, I2)) {
          if (lexlt(d, s, D1, I1)) {
            D2 = D1; I2 = I1;
            if (lexlt(d, s, D0, I0)) { D1 = D0; I1 = I0; D0 = d; I0 = s; }
            else { D1 = d; I1 = s; }
          } else { D2 = d; I2 = s; }
        }
      }
    }
    float r0 = 1.0f / (D0 + 1e-8f);
    float r1 = 1.0f / (D1 + 1e-8f);
    float r2 = 1.0f / (D2 + 1e-8f);
    float rs = (r0 + r1) + r2;
    long qgid = (long)b * NN + n0 + qi;
    idx_out[qgid] = make_int4(I0, I1, I2, 0);
    w_out[qgid] = make_float4(r0 / rs, r1 / rs, r2 / rs, 0.0f);
  }
}

// ---------------- Kernel B: gather + weighted sum + transpose ----------------
// 1024 blocks x 256 threads; 64 queries x 256 channels per block.
__global__ __launch_bounds__(256, 2) void gather_kernel(
    const float* __restrict__ vg, const int4* __restrict__ idx_in,
    const float4* __restrict__ w_in, float* __restrict__ outg) {
#pragma clang fp contract(off)
  __shared__ __align__(16) float tile[64 * TILE_LD];  // 66.56 KB
  __shared__ float sw[64][3];
  __shared__ int si[64][3];

  const int tid = threadIdx.x;
  const int blk = blockIdx.x;
  const int b = blk >> 8;
  const int n0 = (blk & 255) << 6;

  if (tid < 64) {
    long qgid = (long)b * NN + n0 + tid;
    int4 I = idx_in[qgid];
    float4 W = w_in[qgid];
    si[tid][0] = I.x; si[tid][1] = I.y; si[tid][2] = I.z;
    sw[tid][0] = W.x; sw[tid][1] = W.y; sw[tid][2] = W.z;
  }
  __syncthreads();

  const int wv = tid >> 6;    // wave id 0..3
  const int lane = tid & 63;  // lane = channel float4-block
  const float* vb = vg + (long)b * SS * CC;

  for (int i = 0; i < 16; ++i) {
    int qs = wv * 16 + i;
    float w0 = sw[qs][0], w1 = sw[qs][1], w2 = sw[qs][2];
    const float4* r0p = (const float4*)(vb + (long)si[qs][0] * CC);
    const float4* r1p = (const float4*)(vb + (long)si[qs][1] * CC);
    const float4* r2p = (const float4*)(vb + (long)si[qs][2] * CC);
    float4 a0 = r0p[lane], a1 = r1p[lane], a2 = r2p[lane];
    float4 acc;
    acc.x = (w0 * a0.x + w1 * a1.x) + w2 * a2.x;
    acc.y = (w0 * a0.y + w1 * a1.y) + w2 * a2.y;
    acc.z = (w0 * a0.z + w1 * a1.z) + w2 * a2.z;
    acc.w = (w0 * a0.w + w1 * a1.w) + w2 * a2.w;
    *(float4*)&tile[qs * TILE_LD + lane * 4] = acc;
  }
  __syncthreads();
  {
    int qs2 = tid & 63;  // lane-fastest over n for coalescing
    int cb = tid >> 6;   // 0..3
    long nout = (long)n0 + qs2;
    for (int it = 0; it < 64; ++it) {
      int cch = cb + it * 4;
      outg[((long)(b * CC + cch)) * NN + nout] = tile[qs2 * TILE_LD + cch];
    }
  }
}

extern "C" void kernel_launch(void* const* d_in, const int* in_sizes, int n_in,
                              void* d_out, int out_size, void* d_ws, size_t ws_size,
                              hipStream_t stream) {
  const float* q = (const float*)d_in[0];
  const float* k = (const float*)d_in[1];
  const float* v = (const float*)d_in[2];
  float* out = (float*)d_out;
  int4* idx_ws = (int4*)d_ws;                                    // 1 MB
  float4* w_ws = (float4*)((char*)d_ws + (size_t)BB * NN * 16);  // 1 MB
  hipLaunchKernelGGL(scan_kernel, dim3(512), dim3(256), 0, stream, q, k, idx_ws, w_ws);
  hipLaunchKernelGGL(gather_kernel, dim3(1024), dim3(256), 0, stream, v, idx_ws, w_ws, out);
}

// Round 3
// 232.284 us; speedup vs baseline: 1.4565x; 1.4565x over previous
//
#include <hip/hip_runtime.h>

#define BB 4
#define NN 16384
#define SS 4096
#define CC 256
#define SEG 1024    // candidates per scan block (S split 4-way)
#define RQ 4        // queries per thread (register-tiled)
#define TILE_LD 260 // padded leading dim for out-transpose tile

__device__ __forceinline__ bool lexlt(float da, int ia, float db, int ib) {
  // strict (d, idx) lexicographic order — matches jax.lax.top_k tie-break
  return (da < db) || ((da == db) && (ia < ib));
}

// ---------------- Kernel A: partial top-3 scan over one S-segment ----------------
// Grid 2048 = b(4) x seg(4) x nblk(128); 256 threads; 128 queries/block x 1024 cands.
// 8 blocks/CU (exactly fills 256 CUs), LDS 16 KB, VGPR capped at 64.
__global__ __launch_bounds__(256, 8) void scan_kernel(
    const float* __restrict__ qg, const float* __restrict__ kg,
    float4* __restrict__ dpart, int4* __restrict__ ipart) {
#pragma clang fp contract(off)
  __shared__ __align__(16) float4 kpts[SEG];  // 16 KB
  float* md = (float*)kpts;                   // [4][32][4][3] floats (6 KB), overlaid
  int* mi = (int*)((char*)kpts + 6144);       // [4][32][4][3] ints (6 KB)

  const int tid = threadIdx.x;
  const int blk = blockIdx.x;
  const int b = blk >> 9;
  const int seg = (blk >> 7) & 3;
  const int n0 = (blk & 127) << 7;
  const int qlane = tid & 31;  // 32 query-lanes
  const int g = tid >> 5;      // 8 s-groups (2 per wave)

  float qx[RQ], qy[RQ], qz[RQ], qq[RQ];
  float d0[RQ], d1[RQ], d2[RQ];
  int i0[RQ], i1[RQ], i2[RQ];
#pragma unroll
  for (int j = 0; j < RQ; ++j) {
    int n = n0 + qlane + 32 * j;
    const float* qp = qg + ((long)b * NN + n) * 3;
    qx[j] = qp[0]; qy[j] = qp[1]; qz[j] = qp[2];
    qq[j] = (qx[j] * qx[j] + qy[j] * qy[j]) + qz[j] * qz[j];  // np sum order
    d0[j] = 3.4e38f; d1[j] = 3.4e38f; d2[j] = 3.4e38f;
    i0[j] = 0; i1[j] = 0; i2[j] = 0;
  }

  // ---- stage this segment's 1024 points as {x,y,z,kk} ----
  {
    const float* kb = kg + ((long)b * SS + (long)seg * SEG) * 3;
    const float4* src = (const float4*)kb + tid * 3;
    float4 f0 = src[0], f1 = src[1], f2 = src[2];
    float px[4] = {f0.x, f0.w, f1.z, f2.y};
    float py[4] = {f0.y, f1.x, f1.w, f2.z};
    float pz[4] = {f0.z, f1.y, f2.x, f2.w};
#pragma unroll
    for (int m = 0; m < 4; ++m) {
      float kk = (px[m] * px[m] + py[m] * py[m]) + pz[m] * pz[m];
      kpts[tid * 4 + m] = make_float4(px[m], py[m], pz[m], kk);
    }
  }
  __syncthreads();

  const int sbase = seg * SEG + g * 128;
#pragma unroll 2
  for (int i = 0; i < 128; ++i) {
    float4 kp = kpts[g * 128 + i];
    const int s = sbase + i;
#pragma unroll
    for (int j = 0; j < RQ; ++j) {
      // exact np replication: d = qq - 2*dot + kk, left-to-right, no contract.
      float dot = (qx[j] * kp.x + qy[j] * kp.y) + qz[j] * kp.z;
      float d = __builtin_fmaf(dot, -2.0f, qq[j]) + kp.w;
      bool k2 = d < d2[j];
      bool k1 = d < d1[j];
      bool k0 = d < d0[j];
      // sorted invariant d0<=d1<=d2 makes med3 the exact shifted value
      float nd2 = __builtin_amdgcn_fmed3f(d, d1[j], d2[j]);
      float nd1 = __builtin_amdgcn_fmed3f(d, d0[j], d1[j]);
      float nd0 = fminf(d, d0[j]);
      i2[j] = k1 ? i1[j] : (k2 ? s : i2[j]);
      i1[j] = k0 ? i0[j] : (k1 ? s : i1[j]);
      i0[j] = k0 ? s : i0[j];
      d2[j] = nd2; d1[j] = nd1; d0[j] = nd0;
    }
  }

  // ---- intra-wave pair merge: lane L and L^32 hold the same 4 queries ----
#pragma unroll
  for (int j = 0; j < RQ; ++j) {
    float E0 = __shfl_xor(d0[j], 32), E1 = __shfl_xor(d1[j], 32), E2 = __shfl_xor(d2[j], 32);
    int F0 = __shfl_xor(i0[j], 32), F1 = __shfl_xor(i1[j], 32), F2 = __shfl_xor(i2[j], 32);
    float A0 = d0[j], A1 = d1[j], A2 = d2[j];
    int B0 = i0[j], B1 = i1[j], B2 = i2[j];
    bool t = lexlt(E0, F0, A0, B0);
    float r0 = t ? E0 : A0; int s0 = t ? F0 : B0;
    float nA0 = t ? A0 : A1, nA1 = t ? A1 : A2;
    int nB0 = t ? B0 : B1, nB1 = t ? B1 : B2;
    float nE0 = t ? E1 : E0, nE1 = t ? E2 : E1;
    int nF0 = t ? F1 : F0, nF1 = t ? F2 : F1;
    bool u = lexlt(nE0, nF0, nA0, nB0);
    float r1 = u ? nE0 : nA0; int s1 = u ? nF0 : nB0;
    float mA0 = u ? nA0 : nA1; int mB0 = u ? nB0 : nB1;
    float mE0 = u ? nE1 : nE0; int mF0 = u ? nF1 : nF0;
    bool w = lexlt(mE0, mF0, mA0, mB0);
    float r2 = w ? mE0 : mA0; int s2 = w ? mF0 : mB0;
    d0[j] = r0; d1[j] = r1; d2[j] = r2;
    i0[j] = s0; i1[j] = s1; i2[j] = s2;
  }

  __syncthreads();  // all kpts reads done; md/mi overlay kpts
  if ((tid & 63) < 32) {
    const int wv = tid >> 6;
#pragma unroll
    for (int j = 0; j < RQ; ++j) {
      int base = (((wv * 32) + qlane) * RQ + j) * 3;
      md[base + 0] = d0[j]; md[base + 1] = d1[j]; md[base + 2] = d2[j];
      mi[base + 0] = i0[j]; mi[base + 1] = i1[j]; mi[base + 2] = i2[j];
    }
  }
  __syncthreads();

  if (tid < 128) {
    const int qi = tid;
    const int ql = qi & 31, jj = qi >> 5;
    float D0 = 3.4e38f, D1 = 3.4e38f, D2 = 3.4e38f;
    int I0 = -1, I1 = -1, I2 = -1;
    for (int wv = 0; wv < 4; ++wv) {
      int base = ((wv * 32 + ql) * RQ + jj) * 3;
      for (int r = 0; r < 3; ++r) {
        float d = md[base + r];
        int s = mi[base + r];
        if (lexlt(d, s, D2, I2)) {
          if (lexlt(d, s, D1, I1)) {
            D2 = D1; I2 = I1;
            if (lexlt(d, s, D0, I0)) { D1 = D0; I1 = I0; D0 = d; I0 = s; }
            else { D1 = d; I1 = s; }
          } else { D2 = d; I2 = s; }
        }
      }
    }
    long gid = (long)b * NN + n0 + qi;
    dpart[gid * 4 + seg] = make_float4(D0, D1, D2, 0.0f);
    ipart[gid * 4 + seg] = make_int4(I0, I1, I2, 0);
  }
}

// ---------------- Kernel B: merge partials + gather + transpose ----------------
// Grid 2048 = b(4) x nblk(512); 32 queries x 256 channels per block; 4 blocks/CU.
__global__ __launch_bounds__(256, 4) void gather_kernel(
    const float* __restrict__ vg, const float4* __restrict__ dpart,
    const int4* __restrict__ ipart, float* __restrict__ outg) {
#pragma clang fp contract(off)
  __shared__ __align__(16) float tile[32 * TILE_LD];  // 33.28 KB
  __shared__ float sw[32][3];
  __shared__ int si[32][3];

  const int tid = threadIdx.x;
  const int blk = blockIdx.x;
  const int b = blk >> 9;
  const int n0 = (blk & 511) << 5;

  if (tid < 32) {
    long gid = (long)b * NN + n0 + tid;
    float D0 = 3.4e38f, D1 = 3.4e38f, D2 = 3.4e38f;
    int I0 = -1, I1 = -1, I2 = -1;
#pragma unroll
    for (int seg = 0; seg < 4; ++seg) {
      float4 dv = dpart[gid * 4 + seg];
      int4 iv = ipart[gid * 4 + seg];
      float ds_[3] = {dv.x, dv.y, dv.z};
      int is_[3] = {iv.x, iv.y, iv.z};
      for (int r = 0; r < 3; ++r) {
        float d = ds_[r];
        int s = is_[r];
        if (lexlt(d, s, D2, I2)) {
          if (lexlt(d, s, D1, I1)) {
            D2 = D1; I2 = I1;
            if (lexlt(d, s, D0, I0)) { D1 = D0; I1 = I0; D0 = d; I0 = s; }
            else { D1 = d; I1 = s; }
          } else { D2 = d; I2 = s; }
        }
      }
    }
    // weights exactly as ref: recip = 1/(d+1e-8) on ascending dists, then normalize
    float r0 = 1.0f / (D0 + 1e-8f);
    float r1 = 1.0f / (D1 + 1e-8f);
    float r2 = 1.0f / (D2 + 1e-8f);
    float rs = (r0 + r1) + r2;
    sw[tid][0] = r0 / rs; sw[tid][1] = r1 / rs; sw[tid][2] = r2 / rs;
    si[tid][0] = I0; si[tid][1] = I1; si[tid][2] = I2;
  }
  __syncthreads();

  const int wv = tid >> 6;    // wave id 0..3
  const int lane = tid & 63;  // lane = channel float4-block
  const float* vb = vg + (long)b * SS * CC;

#pragma unroll 2
  for (int i = 0; i < 8; ++i) {
    int qs = wv * 8 + i;
    float w0 = sw[qs][0], w1 = sw[qs][1], w2 = sw[qs][2];
    const float4* r0p = (const float4*)(vb + (long)si[qs][0] * CC);
    const float4* r1p = (const float4*)(vb + (long)si[qs][1] * CC);
    const float4* r2p = (const float4*)(vb + (long)si[qs][2] * CC);
    float4 a0 = r0p[lane], a1 = r1p[lane], a2 = r2p[lane];
    float4 acc;
    acc.x = (w0 * a0.x + w1 * a1.x) + w2 * a2.x;
    acc.y = (w0 * a0.y + w1 * a1.y) + w2 * a2.y;
    acc.z = (w0 * a0.z + w1 * a1.z) + w2 * a2.z;
    acc.w = (w0 * a0.w + w1 * a1.w) + w2 * a2.w;
    *(float4*)&tile[qs * TILE_LD + lane * 4] = acc;
  }
  __syncthreads();
  {
    int qs2 = tid & 31;  // lane-fastest over n for coalescing
    int cb = tid >> 5;   // 0..7
    long nout = (long)n0 + qs2;
    for (int it = 0; it < 32; ++it) {
      int cch = cb + it * 8;
      outg[((long)(b * CC + cch)) * NN + nout] = tile[qs2 * TILE_LD + cch];
    }
  }
}

extern "C" void kernel_launch(void* const* d_in, const int* in_sizes, int n_in,
                              void* d_out, int out_size, void* d_ws, size_t ws_size,
                              hipStream_t stream) {
  const float* q = (const float*)d_in[0];
  const float* k = (const float*)d_in[1];
  const float* v = (const float*)d_in[2];
  float* out = (float*)d_out;
  float4* dpart = (float4*)d_ws;                                          // 4 MB
  int4* ipart = (int4*)((char*)d_ws + (size_t)BB * NN * 4 * 16);          // 4 MB
  hipLaunchKernelGGL(scan_kernel, dim3(2048), dim3(256), 0, stream, q, k, dpart, ipart);
  hipLaunchKernelGGL(gather_kernel, dim3(2048), dim3(256), 0, stream, v, dpart, ipart, out);
}